// Round 5
// baseline (3530.773 us; speedup 1.0000x reference)
//
#include <hip/hip_runtime.h>
#include <hip/hip_bf16.h>
#include <cstdint>

#define T_DIM 1024
#define B_DIM 64
#define IN_DIM 32
#define EMB_DIM 64
#define HID_DIM 128
#define K_TAPS 16
#define OUT_DIM 32
#define G4 (4*HID_DIM)          // 512 packed gates [i,o,c,d]
#define MROWS (T_DIM*B_DIM)     // 65536

__device__ __forceinline__ float sigmoidf_(float x) { return 1.0f / (1.0f + expf(-x)); }

// ---------------------------------------------------------------------------
// Small weight-combine GEMM: C[M2 x 512] = A[M2 x K2] @ Bm[K2 x 512]
// grid = M2 blocks, 512 threads
__global__ void gemm_small(const float* __restrict__ A, const float* __restrict__ Bm,
                           float* __restrict__ C, int K2)
{
    int i = blockIdx.x, j = threadIdx.x;
    float acc = 0.f;
    for (int k = 0; k < K2; ++k) acc += A[i * K2 + k] * Bm[k * G4 + j];
    C[i * G4 + j] = acc;
}

// bc[j] = badd[j] + sum_k bvec[k] * Bm[k*512 + j]   (1 block, 512 threads)
__global__ void bias_comb(const float* __restrict__ bvec, const float* __restrict__ Bm,
                          const float* __restrict__ badd, float* __restrict__ bc, int K2)
{
    int j = threadIdx.x;
    float acc = badd[j];
    for (int k = 0; k < K2; ++k) acc += bvec[k] * Bm[k * G4 + j];
    bc[j] = acc;
}

// ---------------------------------------------------------------------------
// Wide GEMM: C[MROWS x 512] = A[MROWS x KK] @ W[KK x 512] + bias
// Thread j holds W column j in registers; A rows staged in LDS.
template<int KK, int ROWS>
__global__ __launch_bounds__(512) void gemm_wide(
    const float* __restrict__ A, const float* __restrict__ W,
    const float* __restrict__ bias, float* __restrict__ C)
{
    __shared__ float a_lds[ROWS * KK];
    const int j = threadIdx.x;
    const size_t row0 = (size_t)blockIdx.x * ROWS;

    float w[KK];
#pragma unroll
    for (int k = 0; k < KK; ++k) w[k] = W[k * G4 + j];
    const float bj = bias[j];

    const float* Ab = A + row0 * KK;
    for (int idx = j * 4; idx < ROWS * KK; idx += 512 * 4)
        *(float4*)&a_lds[idx] = *(const float4*)&Ab[idx];
    __syncthreads();

#pragma unroll 1
    for (int r = 0; r < ROWS; ++r) {
        float acc = bj;
#pragma unroll
        for (int k = 0; k < KK; ++k) acc += a_lds[r * KK + k] * w[k];
        C[(row0 + r) * G4 + j] = acc;
    }
}

// ---------------------------------------------------------------------------
// Output projection: C[MROWS x 32] = H[MROWS x 128] @ Wo[128 x 32] + bo
// 256 threads, 64 rows per block.
__global__ __launch_bounds__(256) void gemm_out(
    const float* __restrict__ H, const float* __restrict__ Wo,
    const float* __restrict__ bo, float* __restrict__ C)
{
    __shared__ float h_lds[64 * HID_DIM];
    __shared__ float wo_lds[HID_DIM * OUT_DIM];
    const int tid = threadIdx.x;
    const size_t row0 = (size_t)blockIdx.x * 64;

    const float* Hb = H + row0 * HID_DIM;
    for (int idx = tid * 4; idx < 64 * HID_DIM; idx += 256 * 4)
        *(float4*)&h_lds[idx] = *(const float4*)&Hb[idx];
    for (int idx = tid * 4; idx < HID_DIM * OUT_DIM; idx += 256 * 4)
        *(float4*)&wo_lds[idx] = *(const float4*)&Wo[idx];
    __syncthreads();

    const int col = tid & 31, rg = tid >> 5;
    const float bc = bo[col];
    for (int rr = 0; rr < 8; ++rr) {
        const int row = rg + rr * 8;
        float acc = bc;
#pragma unroll
        for (int k = 0; k < HID_DIM; ++k)
            acc += h_lds[row * HID_DIM + k] * wo_lds[k * OUT_DIM + col];
        C[(row0 + row) * OUT_DIM + col] = acc;
    }
}

// ---------------------------------------------------------------------------
// Recurrent scan: one workgroup per batch element, 512 threads.
// Thread j owns gate column j; Wh column j lives in 128 VGPRs for all steps.
__global__ __launch_bounds__(512) void scan_kernel(
    const float* __restrict__ XG, const float* __restrict__ Wh,
    float* __restrict__ Hout)
{
    const int b = blockIdx.x;
    const int j = threadIdx.x;

    __shared__ float h_lds[HID_DIM];
    __shared__ float g_lds[G4];
    __shared__ float buf[K_TAPS][HID_DIM];   // circular candidate buffer

    float w[HID_DIM];
#pragma unroll
    for (int k = 0; k < HID_DIM; ++k) w[k] = Wh[k * G4 + j];

    if (j < HID_DIM) {
        h_lds[j] = 0.f;
#pragma unroll
        for (int p = 0; p < K_TAPS; ++p) buf[p][j] = 0.f;
    }
    __syncthreads();

    const float* xgp = XG + (size_t)b * G4 + j;
    float xg_next = xgp[0];

    for (int t = 0; t < T_DIM; ++t) {
        const float xg = xg_next;
        if (t + 1 < T_DIM) xg_next = xgp[(size_t)(t + 1) * B_DIM * G4];  // prefetch

        float acc = xg;
#pragma unroll
        for (int k = 0; k < HID_DIM; ++k) acc += h_lds[k] * w[k];
        g_lds[j] = acc;
        __syncthreads();   // all matvec reads of h done; g complete

        if (j < HID_DIM) {
            const float ig = sigmoidf_(g_lds[j]);
            const float og = sigmoidf_(g_lds[HID_DIM + j]);
            const float cg = g_lds[2 * HID_DIM + j];
            const float dg = g_lds[3 * HID_DIM + j];
            const float d  = 0.5f * sigmoidf_(dg);
            const float hc = ig * tanhf(cg);

            const int pos = t & (K_TAPS - 1);
            buf[pos][j] = hc;

            float c = hc;        // w_0 = 1
            float wj = 1.f;
#pragma unroll
            for (int jj = 1; jj < K_TAPS; ++jj) {
                wj *= (jj - 1.0f + d) * (1.0f / jj);
                c += wj * buf[(pos - jj + K_TAPS) & (K_TAPS - 1)][j];
            }
            const float hn = og * tanhf(c);
            h_lds[j] = hn;
            Hout[(size_t)t * B_DIM * HID_DIM + b * HID_DIM + j] = hn;
        }
        __syncthreads();   // h ready for next step
    }
}

// ---------------------------------------------------------------------------
extern "C" void kernel_launch(void* const* d_in, const int* in_sizes, int n_in,
                              void* d_out, int out_size, void* d_ws, size_t ws_size,
                              hipStream_t stream)
{
    const float* inputs = (const float*)d_in[0];   // [T,B,32]
    const float* W_emb  = (const float*)d_in[1];   // [32,64]
    const float* b_emb  = (const float*)d_in[2];   // [64]
    const float* Wx0    = (const float*)d_in[3];   // [64,512]
    const float* Wh0    = (const float*)d_in[4];   // [128,512]
    const float* b0     = (const float*)d_in[5];   // [512]
    const float* Wo0    = (const float*)d_in[6];   // [128,128]
    const float* bo0    = (const float*)d_in[7];   // [128]
    const float* Wx1    = (const float*)d_in[8];   // [128,512]
    const float* Wh1    = (const float*)d_in[9];   // [128,512]
    const float* b1     = (const float*)d_in[10];  // [512]
    const float* Wo1    = (const float*)d_in[11];  // [128,32]
    const float* bo1    = (const float*)d_in[12];  // [32]
    float* out = (float*)d_out;

    float* ws   = (float*)d_ws;
    float* XG   = ws;                                   // 65536*512 (reused both layers)
    float* Hbuf = XG + (size_t)MROWS * G4;              // 65536*128 (reused both layers)
    float* W0c  = Hbuf + (size_t)MROWS * HID_DIM;       // 32*512
    float* b0c  = W0c + IN_DIM * G4;                    // 512
    float* W1c  = b0c + G4;                             // 128*512
    float* b1c  = W1c + HID_DIM * G4;                   // 512

    // ---- layer 0: collapse embedding into Wx0 ----
    gemm_small<<<IN_DIM, G4, 0, stream>>>(W_emb, Wx0, W0c, EMB_DIM);
    bias_comb<<<1, G4, 0, stream>>>(b_emb, Wx0, b0, b0c, EMB_DIM);
    gemm_wide<IN_DIM, 128><<<MROWS / 128, 512, 0, stream>>>(inputs, W0c, b0c, XG);
    scan_kernel<<<B_DIM, 512, 0, stream>>>(XG, Wh0, Hbuf);

    // ---- layer 1: collapse Wo0 into Wx1 ----
    gemm_small<<<HID_DIM, G4, 0, stream>>>(Wo0, Wx1, W1c, HID_DIM);
    bias_comb<<<1, G4, 0, stream>>>(bo0, Wx1, b1, b1c, HID_DIM);
    gemm_wide<HID_DIM, 64><<<MROWS / 64, 512, 0, stream>>>(Hbuf, W1c, b1c, XG);
    scan_kernel<<<B_DIM, 512, 0, stream>>>(XG, Wh1, Hbuf);

    // ---- output projection ----
    gemm_out<<<MROWS / 64, 256, 0, stream>>>(Hbuf, Wo1, bo1, out);
}

// Round 6
// 2770.810 us; speedup vs baseline: 1.2743x; 1.2743x over previous
//
#include <hip/hip_runtime.h>
#include <hip/hip_bf16.h>
#include <cstdint>

#define T_DIM 1024
#define B_DIM 64
#define IN_DIM 32
#define EMB_DIM 64
#define HID_DIM 128
#define K_TAPS 16
#define OUT_DIM 32
#define G4 (4*HID_DIM)          // 512 packed gates [i,o,c,d]
#define MROWS (T_DIM*B_DIM)     // 65536

typedef _Float16 f16x2 __attribute__((ext_vector_type(2)));
typedef _Float16 f16x8 __attribute__((ext_vector_type(8)));

#if __has_builtin(__builtin_amdgcn_fdot2)
#define FDOT2(a,b,c) __builtin_amdgcn_fdot2((a),(b),(c),false)
#else
#define FDOT2(a,b,c) fmaf((float)(a)[1],(float)(b)[1],fmaf((float)(a)[0],(float)(b)[0],(c)))
#endif

// fast sigmoid/tanh: v_exp_f32 + v_rcp_f32; rel err ~1e-6 (negligible vs 2.1e-4 budget)
__device__ __forceinline__ float fast_sigmoid(float x) {
    return __builtin_amdgcn_rcpf(1.0f + __expf(-x));
}
__device__ __forceinline__ float fast_tanh(float x) {
    return 1.0f - 2.0f * __builtin_amdgcn_rcpf(1.0f + __expf(2.0f * x));
}

// ---------------------------------------------------------------------------
// Small weight-combine GEMM: C[M2 x 512] = A[M2 x K2] @ Bm[K2 x 512]
__global__ void gemm_small(const float* __restrict__ A, const float* __restrict__ Bm,
                           float* __restrict__ C, int K2)
{
    int i = blockIdx.x, j = threadIdx.x;
    float acc = 0.f;
    for (int k = 0; k < K2; ++k) acc += A[i * K2 + k] * Bm[k * G4 + j];
    C[i * G4 + j] = acc;
}

__global__ void bias_comb(const float* __restrict__ bvec, const float* __restrict__ Bm,
                          const float* __restrict__ badd, float* __restrict__ bc, int K2)
{
    int j = threadIdx.x;
    float acc = badd[j];
    for (int k = 0; k < K2; ++k) acc += bvec[k] * Bm[k * G4 + j];
    bc[j] = acc;
}

// ---------------------------------------------------------------------------
// Wide GEMM: C[MROWS x 512] = A[MROWS x KK] @ W[KK x 512] + bias
// No LDS: A-row reads are wave-uniform -> s_load (SMEM pipe) / L1 broadcast.
// W column j lives in registers. 4 accumulators for ILP.
template<int KK, int ROWS>
__global__ __launch_bounds__(512) void gemm_wide(
    const float* __restrict__ A, const float* __restrict__ W,
    const float* __restrict__ bias, float* __restrict__ C)
{
    const int j = threadIdx.x;
    const size_t row0 = (size_t)blockIdx.x * ROWS;

    float w[KK];
#pragma unroll
    for (int k = 0; k < KK; ++k) w[k] = W[k * G4 + j];
    const float bj = bias[j];

    const float* Ar = A + row0 * KK;
#pragma unroll 1
    for (int r = 0; r < ROWS; ++r, Ar += KK) {
        float a0 = bj, a1 = 0.f, a2 = 0.f, a3 = 0.f;
#pragma unroll
        for (int k = 0; k < KK; k += 4) {
            a0 = fmaf(Ar[k + 0], w[k + 0], a0);
            a1 = fmaf(Ar[k + 1], w[k + 1], a1);
            a2 = fmaf(Ar[k + 2], w[k + 2], a2);
            a3 = fmaf(Ar[k + 3], w[k + 3], a3);
        }
        C[(row0 + r) * G4 + j] = (a0 + a1) + (a2 + a3);
    }
}

// ---------------------------------------------------------------------------
// Output projection: C[MROWS x 32] = H[MROWS x 128] @ Wo[128 x 32] + bo
__global__ __launch_bounds__(256) void gemm_out(
    const float* __restrict__ H, const float* __restrict__ Wo,
    const float* __restrict__ bo, float* __restrict__ C)
{
    __shared__ float h_lds[64 * HID_DIM];
    __shared__ float wo_lds[HID_DIM * OUT_DIM];
    const int tid = threadIdx.x;
    const size_t row0 = (size_t)blockIdx.x * 64;

    const float* Hb = H + row0 * HID_DIM;
    for (int idx = tid * 4; idx < 64 * HID_DIM; idx += 256 * 4)
        *(float4*)&h_lds[idx] = *(const float4*)&Hb[idx];
    for (int idx = tid * 4; idx < HID_DIM * OUT_DIM; idx += 256 * 4)
        *(float4*)&wo_lds[idx] = *(const float4*)&Wo[idx];
    __syncthreads();

    const int col = tid & 31, rg = tid >> 5;
    const float bc = bo[col];
    for (int rr = 0; rr < 8; ++rr) {
        const int row = rg + rr * 8;
        float acc = bc;
#pragma unroll
        for (int k = 0; k < HID_DIM; ++k)
            acc += h_lds[row * HID_DIM + k] * wo_lds[k * OUT_DIM + col];
        C[(row0 + row) * OUT_DIM + col] = acc;
    }
}

// ---------------------------------------------------------------------------
// Recurrent scan: one workgroup per batch element, 512 threads.
// h stored in LDS as f16 (halves LDS instr count); matvec via v_dot2_f32_f16;
// each thread applies its own gate's transcendental (no barrier before it).
// 2 barriers/step. Thread j owns gate column j; Wh col j in 64 f16x2 VGPRs.
__global__ __launch_bounds__(512) void scan_kernel(
    const float* __restrict__ XG, const float* __restrict__ Wh,
    float* __restrict__ Hout)
{
    const int b = blockIdx.x;
    const int j = threadIdx.x;
    const int gate = j >> 7;             // 0:i 1:o 2:c 3:d

    __shared__ __align__(16) _Float16 h16[HID_DIM];
    __shared__ float t_lds[G4];          // per-gate transcendental results
    __shared__ float buf[K_TAPS][HID_DIM];

    // Wh column j -> f16x2 registers (coalesced f32 loads, cvt once)
    f16x2 w2[HID_DIM / 2];
#pragma unroll
    for (int kk = 0; kk < HID_DIM / 2; ++kk) {
        f16x2 p;
        p[0] = (_Float16)Wh[(2 * kk + 0) * G4 + j];
        p[1] = (_Float16)Wh[(2 * kk + 1) * G4 + j];
        w2[kk] = p;
    }

    if (j < HID_DIM) {
        h16[j] = (_Float16)0.f;
#pragma unroll
        for (int p = 0; p < K_TAPS; ++p) buf[p][j] = 0.f;
    }
    __syncthreads();

    const float* xgp = XG + (size_t)b * G4 + j;
    float xg_next = xgp[0];

    for (int t = 0; t < T_DIM; ++t) {
        const float xg = xg_next;
        if (t + 1 < T_DIM) xg_next = xgp[(size_t)(t + 1) * B_DIM * G4];  // prefetch

        // ---- phase A: g_j = xg_j + <h, Wh[:,j]>  (f16 dot2, 4 accumulators)
        float a0 = 0.f, a1 = 0.f, a2 = 0.f, a3 = 0.f;
#pragma unroll
        for (int k8 = 0; k8 < HID_DIM / 8; ++k8) {      // 16 b128 broadcast reads
            union { f16x8 v8; f16x2 v2[4]; } u;
            u.v8 = ((const f16x8*)h16)[k8];
            a0 = FDOT2(u.v2[0], w2[4 * k8 + 0], a0);
            a1 = FDOT2(u.v2[1], w2[4 * k8 + 1], a1);
            a2 = FDOT2(u.v2[2], w2[4 * k8 + 2], a2);
            a3 = FDOT2(u.v2[3], w2[4 * k8 + 3], a3);
        }
        const float g = xg + ((a0 + a1) + (a2 + a3));

        // ---- phase B: own-gate transcendental (thread j owns g_j; no barrier)
        float tv;
        if (gate == 2)      tv = fast_tanh(g);
        else if (gate == 3) tv = 0.5f * fast_sigmoid(g);
        else                tv = fast_sigmoid(g);
        t_lds[j] = tv;
        __syncthreads();   // t_lds complete; all h16 reads of this step done

        // ---- phase C: combine + fractional filter on threads 0..127
        if (j < HID_DIM) {
            const float ig = t_lds[j];
            const float og = t_lds[HID_DIM + j];
            const float tc = t_lds[2 * HID_DIM + j];
            const float d  = t_lds[3 * HID_DIM + j];
            const float hc = ig * tc;

            const int pos = t & (K_TAPS - 1);
            buf[pos][j] = hc;

            float c = hc;        // w_0 = 1
            float wj = 1.f;
#pragma unroll
            for (int jj = 1; jj < K_TAPS; ++jj) {
                wj *= (jj - 1.0f + d) * (1.0f / jj);
                c = fmaf(wj, buf[(pos - jj + K_TAPS) & (K_TAPS - 1)][j], c);
            }
            const float hn = og * fast_tanh(c);
            h16[j] = (_Float16)hn;
            Hout[(size_t)t * (B_DIM * HID_DIM) + b * HID_DIM + j] = hn;
        }
        __syncthreads();   // h16 ready for next step
    }
}

// ---------------------------------------------------------------------------
extern "C" void kernel_launch(void* const* d_in, const int* in_sizes, int n_in,
                              void* d_out, int out_size, void* d_ws, size_t ws_size,
                              hipStream_t stream)
{
    const float* inputs = (const float*)d_in[0];   // [T,B,32]
    const float* W_emb  = (const float*)d_in[1];   // [32,64]
    const float* b_emb  = (const float*)d_in[2];   // [64]
    const float* Wx0    = (const float*)d_in[3];   // [64,512]
    const float* Wh0    = (const float*)d_in[4];   // [128,512]
    const float* b0     = (const float*)d_in[5];   // [512]
    const float* Wo0    = (const float*)d_in[6];   // [128,128]
    const float* bo0    = (const float*)d_in[7];   // [128]
    const float* Wx1    = (const float*)d_in[8];   // [128,512]
    const float* Wh1    = (const float*)d_in[9];   // [128,512]
    const float* b1     = (const float*)d_in[10];  // [512]
    const float* Wo1    = (const float*)d_in[11];  // [128,32]
    const float* bo1    = (const float*)d_in[12];  // [32]
    float* out = (float*)d_out;

    float* ws   = (float*)d_ws;
    float* XG   = ws;                                   // 65536*512 (reused both layers)
    float* Hbuf = XG + (size_t)MROWS * G4;              // 65536*128 (reused both layers)
    float* W0c  = Hbuf + (size_t)MROWS * HID_DIM;       // 32*512
    float* b0c  = W0c + IN_DIM * G4;                    // 512
    float* W1c  = b0c + G4;                             // 128*512
    float* b1c  = W1c + HID_DIM * G4;                   // 512

    // ---- layer 0: collapse embedding into Wx0 ----
    gemm_small<<<IN_DIM, G4, 0, stream>>>(W_emb, Wx0, W0c, EMB_DIM);
    bias_comb<<<1, G4, 0, stream>>>(b_emb, Wx0, b0, b0c, EMB_DIM);
    gemm_wide<IN_DIM, 64><<<MROWS / 64, 512, 0, stream>>>(inputs, W0c, b0c, XG);
    scan_kernel<<<B_DIM, 512, 0, stream>>>(XG, Wh0, Hbuf);

    // ---- layer 1: collapse Wo0 into Wx1 ----
    gemm_small<<<HID_DIM, G4, 0, stream>>>(Wo0, Wx1, W1c, HID_DIM);
    bias_comb<<<1, G4, 0, stream>>>(bo0, Wx1, b1, b1c, HID_DIM);
    gemm_wide<HID_DIM, 32><<<MROWS / 32, 512, 0, stream>>>(Hbuf, W1c, b1c, XG);
    scan_kernel<<<B_DIM, 512, 0, stream>>>(XG, Wh1, Hbuf);

    // ---- output projection ----
    gemm_out<<<MROWS / 64, 256, 0, stream>>>(Hbuf, Wo1, bo1, out);
}

// Round 9
// 1506.331 us; speedup vs baseline: 2.3440x; 1.8394x over previous
//
#include <hip/hip_runtime.h>
#include <hip/hip_bf16.h>
#include <cstdint>
#include <type_traits>

#define T_DIM 1024
#define B_DIM 64
#define IN_DIM 32
#define EMB_DIM 64
#define HID_DIM 128
#define K_TAPS 16
#define OUT_DIM 32
#define G4 (4*HID_DIM)          // 512 packed gates [i,o,c,d]
#define MROWS (T_DIM*B_DIM)     // 65536

typedef _Float16 half8 __attribute__((ext_vector_type(8)));
typedef _Float16 half4 __attribute__((ext_vector_type(4)));
typedef float f32x4 __attribute__((ext_vector_type(4)));

#define MFMA16(a,b,c) __builtin_amdgcn_mfma_f32_16x16x32_f16((a),(b),(c),0,0,0)

// fast sigmoid/tanh via v_exp_f32 + v_rcp_f32 (rel err ~1e-6)
__device__ __forceinline__ float fast_sigmoid(float x) {
    return __builtin_amdgcn_rcpf(1.0f + __expf(-x));
}
__device__ __forceinline__ float fast_tanh(float x) {
    return 1.0f - 2.0f * __builtin_amdgcn_rcpf(1.0f + __expf(2.0f * x));
}

// ---------------------------------------------------------------------------
// Small weight-combine GEMM: C[M2 x 512] = A[M2 x K2] @ Bm[K2 x 512]
__global__ void gemm_small(const float* __restrict__ A, const float* __restrict__ Bm,
                           float* __restrict__ C, int K2)
{
    int i = blockIdx.x, j = threadIdx.x;
    float acc = 0.f;
    for (int k = 0; k < K2; ++k) acc += A[i * K2 + k] * Bm[k * G4 + j];
    C[i * G4 + j] = acc;
}

__global__ void bias_comb(const float* __restrict__ bvec, const float* __restrict__ Bm,
                          const float* __restrict__ badd, float* __restrict__ bc, int K2)
{
    int j = threadIdx.x;
    float acc = badd[j];
    for (int k = 0; k < K2; ++k) acc += bvec[k] * Bm[k * G4 + j];
    bc[j] = acc;
}

// ---------------------------------------------------------------------------
// MFMA GEMM: C[M x NSTR](f32) = A[M x KK](TA) @ W[KK x NSTR](f32, cvt f16) + bias
// WG: 256 threads = 4 waves; tile 64(M) x NCOLS(N). Wave w = 16-row M-slab.
// A staged in LDS f16 with +8 pad (row stride 16B-aligned, 2-way max conflict).
template<int KK, int NCOLS, int NSTR, typename TA>
__global__ __launch_bounds__(256) void gemm_mfma(
    const TA* __restrict__ A, const float* __restrict__ W,
    const float* __restrict__ bias, float* __restrict__ C)
{
    constexpr int KT = KK / 32;      // K-tiles
    constexpr int NT = NCOLS / 16;   // N-tiles per wave
    const int bm = blockIdx.x, bn = blockIdx.y;
    const int tid = threadIdx.x;
    const int w = tid >> 6, l = tid & 63, lc = l & 15, lk = l >> 4;

    __shared__ __align__(16) _Float16 aLds[64][KK + 8];

    // ---- stage A tile (64 x KK) -> LDS f16
    if constexpr (std::is_same_v<TA, float>) {
        const float* Ab = A + (size_t)bm * 64 * KK;
        for (int idx = tid * 4; idx < 64 * KK; idx += 1024) {
            const int r = idx / KK, k = idx % KK;
            float4 v = *(const float4*)&Ab[idx];
            half4 h; h[0] = (_Float16)v.x; h[1] = (_Float16)v.y;
            h[2] = (_Float16)v.z; h[3] = (_Float16)v.w;
            *(half4*)&aLds[r][k] = h;
        }
    } else {
        const _Float16* Ab = (const _Float16*)A + (size_t)bm * 64 * KK;
        for (int idx = tid * 8; idx < 64 * KK; idx += 2048) {
            const int r = idx / KK, k = idx % KK;
            *(half8*)&aLds[r][k] = *(const half8*)&Ab[idx];
        }
    }

    // ---- B fragments: W[k][col], col = bn*NCOLS + nt*16 + lc, k = kt*32 + lk*8 + e
    half8 bf[NT][KT];
#pragma unroll
    for (int nt = 0; nt < NT; ++nt)
#pragma unroll
        for (int kt = 0; kt < KT; ++kt) {
            half8 v;
#pragma unroll
            for (int e = 0; e < 8; ++e)
                v[e] = (_Float16)W[(size_t)(kt * 32 + lk * 8 + e) * NSTR + bn * NCOLS + nt * 16 + lc];
            bf[nt][kt] = v;
        }

    __syncthreads();

    // ---- A fragments for this wave's 16-row slab
    half8 af[KT];
#pragma unroll
    for (int kt = 0; kt < KT; ++kt)
        af[kt] = *(const half8*)&aLds[w * 16 + lc][kt * 32 + lk * 8];

    f32x4 acc[NT];
#pragma unroll
    for (int nt = 0; nt < NT; ++nt) acc[nt] = (f32x4){0.f, 0.f, 0.f, 0.f};
#pragma unroll
    for (int nt = 0; nt < NT; ++nt)
#pragma unroll
        for (int kt = 0; kt < KT; ++kt)
            acc[nt] = MFMA16(af[kt], bf[nt][kt], acc[nt]);

    // ---- epilogue: +bias, store (C/D layout: col=lane&15, row=(lane>>4)*4+reg)
#pragma unroll
    for (int nt = 0; nt < NT; ++nt) {
        const int col = bn * NCOLS + nt * 16 + lc;
        const float bv = bias[col];
#pragma unroll
        for (int r = 0; r < 4; ++r) {
            const int row = bm * 64 + w * 16 + lk * 4 + r;
            C[(size_t)row * NSTR + col] = acc[nt][r] + bv;
        }
    }
}

// ---------------------------------------------------------------------------
// Recurrent scan, MFMA matvec with stride-0 A-broadcast trick.
// 1 WG (8 waves) per batch. Wave w owns gate cols {g*128+16w..+15}, g=0..3:
// lane l (l&15=lc) holds all 4 gates of hid=16w+lc (4 redundant copies over l>>4).
// h16 double-buffered in LDS; A-frag rows aliased (all 16 rows read same 16B).
// Ring buffer in VGPRs via 16x-unrolled t-loop (static indices).
__global__ __launch_bounds__(512) void scan_kernel(
    const float* __restrict__ XG, const float* __restrict__ Wh,
    _Float16* __restrict__ HoutH)
{
    const int b = blockIdx.x;
    const int tid = threadIdx.x;
    const int w = tid >> 6, l = tid & 63, lc = l & 15, lk = l >> 4;
    const int hid = w * 16 + lc;

    __shared__ __align__(16) _Float16 hbuf[2][HID_DIM];

    // B-frags: Wh[k][col], col = gt*128 + hid, k = kt*32 + lk*8 + e  (64 VGPR)
    half8 bf[4][4];
#pragma unroll
    for (int gt = 0; gt < 4; ++gt)
#pragma unroll
        for (int kt = 0; kt < 4; ++kt) {
            half8 v;
#pragma unroll
            for (int e = 0; e < 8; ++e)
                v[e] = (_Float16)Wh[(size_t)(kt * 32 + lk * 8 + e) * G4 + gt * 128 + hid];
            bf[gt][kt] = v;
        }

    float rb[K_TAPS];
#pragma unroll
    for (int p = 0; p < K_TAPS; ++p) rb[p] = 0.f;

    if (tid < HID_DIM) { hbuf[0][tid] = (_Float16)0.f; hbuf[1][tid] = (_Float16)0.f; }
    __syncthreads();

    const float* xgb = XG + (size_t)b * G4;
    float xgp[2][4];
#pragma unroll
    for (int gt = 0; gt < 4; ++gt) xgp[0][gt] = xgb[gt * 128 + hid];
#pragma unroll
    for (int gt = 0; gt < 4; ++gt) xgp[1][gt] = xgb[(size_t)(B_DIM * G4) + gt * 128 + hid];

    for (int tb = 0; tb < T_DIM; tb += K_TAPS) {
#pragma unroll
        for (int p = 0; p < K_TAPS; ++p) {
            const int t = tb + p;
            // ---- A-frags: stride-0 rows -> 4 broadcast b128 reads; all C rows equal
            half8 af0 = *(const half8*)&hbuf[p & 1][ 0 + lk * 8];
            half8 af1 = *(const half8*)&hbuf[p & 1][32 + lk * 8];
            half8 af2 = *(const half8*)&hbuf[p & 1][64 + lk * 8];
            half8 af3 = *(const half8*)&hbuf[p & 1][96 + lk * 8];
            f32x4 a0 = (f32x4){0.f,0.f,0.f,0.f}, a1 = a0, a2 = a0, a3 = a0;
            a0 = MFMA16(af0, bf[0][0], a0); a0 = MFMA16(af1, bf[0][1], a0);
            a0 = MFMA16(af2, bf[0][2], a0); a0 = MFMA16(af3, bf[0][3], a0);
            a1 = MFMA16(af0, bf[1][0], a1); a1 = MFMA16(af1, bf[1][1], a1);
            a1 = MFMA16(af2, bf[1][2], a1); a1 = MFMA16(af3, bf[1][3], a1);
            a2 = MFMA16(af0, bf[2][0], a2); a2 = MFMA16(af1, bf[2][1], a2);
            a2 = MFMA16(af2, bf[2][2], a2); a2 = MFMA16(af3, bf[2][3], a2);
            a3 = MFMA16(af0, bf[3][0], a3); a3 = MFMA16(af1, bf[3][1], a3);
            a3 = MFMA16(af2, bf[3][2], a3); a3 = MFMA16(af3, bf[3][3], a3);

            const float gi = xgp[p & 1][0] + a0[0];
            const float go = xgp[p & 1][1] + a1[0];
            const float gc = xgp[p & 1][2] + a2[0];
            const float gd = xgp[p & 1][3] + a3[0];

            // ---- prefetch xg for t+2 into the slot just consumed
            if (t + 2 < T_DIM) {
#pragma unroll
                for (int gt = 0; gt < 4; ++gt)
                    xgp[p & 1][gt] = xgb[(size_t)(t + 2) * (B_DIM * G4) + gt * 128 + hid];
            }

            // ---- pointwise + fractional filter (in-register, static ring)
            const float ig = fast_sigmoid(gi);
            const float og = fast_sigmoid(go);
            const float d  = 0.5f * fast_sigmoid(gd);
            const float hc = ig * fast_tanh(gc);
            rb[p] = hc;
            float c = hc, wj = 1.f;
#pragma unroll
            for (int jj = 1; jj < K_TAPS; ++jj) {
                wj *= (jj - 1.0f + d) * (1.0f / jj);
                c = fmaf(wj, rb[(p - jj) & (K_TAPS - 1)], c);
            }
            const float hn = og * fast_tanh(c);

            if (lk == 0) {
                hbuf[(p & 1) ^ 1][hid] = (_Float16)hn;
                HoutH[(size_t)t * (B_DIM * HID_DIM) + b * HID_DIM + hid] = (_Float16)hn;
            }
            __syncthreads();   // h(t) visible; all reads of hbuf[p&1] done
        }
    }
}

// ---------------------------------------------------------------------------
extern "C" void kernel_launch(void* const* d_in, const int* in_sizes, int n_in,
                              void* d_out, int out_size, void* d_ws, size_t ws_size,
                              hipStream_t stream)
{
    const float* inputs = (const float*)d_in[0];   // [T,B,32]
    const float* W_emb  = (const float*)d_in[1];   // [32,64]
    const float* b_emb  = (const float*)d_in[2];   // [64]
    const float* Wx0    = (const float*)d_in[3];   // [64,512]
    const float* Wh0    = (const float*)d_in[4];   // [128,512]
    const float* b0     = (const float*)d_in[5];   // [512]
    const float* Wo0    = (const float*)d_in[6];   // [128,128]
    const float* bo0    = (const float*)d_in[7];   // [128]
    const float* Wx1    = (const float*)d_in[8];   // [128,512]
    const float* Wh1    = (const float*)d_in[9];   // [128,512]
    const float* b1     = (const float*)d_in[10];  // [512]
    const float* Wo1    = (const float*)d_in[11];  // [128,32]
    const float* bo1    = (const float*)d_in[12];  // [32]
    float* out = (float*)d_out;

    float* ws = (float*)d_ws;
    float*     XG    = ws;                                          // 65536*512 f32
    _Float16*  HoutH = (_Float16*)(ws + (size_t)MROWS * G4);        // 65536*128 f16
    float*     W0c   = (float*)((char*)HoutH + (size_t)MROWS * HID_DIM * sizeof(_Float16));
    float*     b0c   = W0c + IN_DIM * G4;
    float*     W1c   = b0c + G4;
    float*     b1c   = W1c + HID_DIM * G4;

    // ---- layer 0: collapse embedding into Wx0 ----
    gemm_small<<<IN_DIM, G4, 0, stream>>>(W_emb, Wx0, W0c, EMB_DIM);
    bias_comb<<<1, G4, 0, stream>>>(b_emb, Wx0, b0, b0c, EMB_DIM);
    gemm_mfma<IN_DIM, 64, G4, float>
        <<<dim3(MROWS / 64, G4 / 64), 256, 0, stream>>>(inputs, W0c, b0c, XG);
    scan_kernel<<<B_DIM, 512, 0, stream>>>(XG, Wh0, HoutH);

    // ---- layer 1: collapse Wo0 into Wx1 ----
    gemm_small<<<HID_DIM, G4, 0, stream>>>(Wo0, Wx1, W1c, HID_DIM);
    bias_comb<<<1, G4, 0, stream>>>(bo0, Wx1, b1, b1c, HID_DIM);
    gemm_mfma<HID_DIM, 64, G4, _Float16>
        <<<dim3(MROWS / 64, G4 / 64), 256, 0, stream>>>(HoutH, W1c, b1c, XG);
    scan_kernel<<<B_DIM, 512, 0, stream>>>(XG, Wh1, HoutH);

    // ---- output projection (f16 MFMA, N=32) ----
    gemm_mfma<HID_DIM, OUT_DIM, OUT_DIM, _Float16>
        <<<dim3(MROWS / 64, 1), 256, 0, stream>>>(HoutH, Wo1, bo1, out);
}